// Round 12
// baseline (17879.102 us; speedup 1.0000x reference)
//
#include <hip/hip_runtime.h>
#include <math.h>

// NDDE forward-Euler DDE solve, D=768, N=8192 steps.
// x_{j+1} = x_j + dt * tanh(Wx x_j + Wy x_{j-10} + b),  dt = tau/10.
// Output: trajectory [D][N+1] fp32, out[i*(N+1)+k] = x_k[i].
//
// NUMERICS ARE FROZEN (passes at absmax 16.0 / thr 16.4): fp64-exact dots
// rounded per-dot to fp32; fp32 adds for z; correctly-rounded fp32 tanh via
// fp64; fp32 state update mul-then-add; per-row 32-lane x 24-col ownership,
// FMA order and shuffle tree IDENTICAL to rounds 5/11.
//
// Round 12 = r11 + ONE change: minimum-period sweeps. NT 256->384 (6 waves);
// every thread polls exactly 2 adjacent packs with a single
// global_load_dwordx4 sc0 sc1 (one MALL request), 384 x 2 = 768 exact.
// Sweep = 1 load + 2 tag checks (r11: 3 serialized 8B loads). Waves 4-5 are
// poll/broadcast helpers only. r11 confirmed sweep period is the dominant
// residual term (12->3 loads gave -27%); this takes it to the floor.
// Fallback: after 2048 failed sweeps a lane switches to the r11-proven 8B
// atomic-load poll — no-hang, correctness independent of sc0/sc1 semantics.
//
// Encoded lessons: no fences (r3), no RMWs (r7), no extra detect hop (r9),
// no setprio on spinners (r6), no replication (r8), VGPR must fit weights
// (r4/r10), fewer/larger blocks spill (r10).

#define DD 768
#define NSTEPS 8192
#define NWG 96
#define NT 384
#define ROWS_PER_WG 8
#define COLS_PER_LANE 24
#define RING 16

#define RING_OFF 0   // RING * DD * 8B packs in d_ws

typedef __attribute__((ext_vector_type(4))) unsigned int u32x4;

__device__ __forceinline__ unsigned long long ld_tag(const unsigned long long* p) {
    return __hip_atomic_load(p, __ATOMIC_RELAXED, __HIP_MEMORY_SCOPE_AGENT);
}

// One 16B coherent load of two (value|tag) packs: v.x=val0 v.y=tag0
// v.z=val1 v.w=tag1. sc0 sc1 -> read from the device coherence point.
__device__ __forceinline__ u32x4 ld_pair(const unsigned long long* p) {
    u32x4 v;
    asm volatile("global_load_dwordx4 %0, %1, off sc0 sc1\n\t"
                 "s_waitcnt vmcnt(0)"
                 : "=v"(v) : "v"(p) : "memory");
    return v;
}

__global__ __launch_bounds__(NT, 1)
void ndde_kernel(const float* __restrict__ x0,
                 const float* __restrict__ tau,
                 const float* __restrict__ Wx,
                 const float* __restrict__ Wy,
                 const float* __restrict__ b,
                 float* __restrict__ out,
                 unsigned long long* __restrict__ ring)
{
    // Transposed f32 LDS history (r5): column i at hist[slot][(i%24)*32+i/24].
    // Dot-reads bank-conflict-free (bank = lane).
    __shared__ float hist[RING][DD];     // 48 KB

    const int tid  = threadIdx.x;
    const int g    = blockIdx.x;
    const bool comp = (tid < 256);       // waves 0-3 compute; 4-5 poll-only
    const int r    = tid >> 5;           // local row 0..7 (compute threads)
    const int c    = tid & 31;           // lane-within-row 0..31
    const int row  = g * ROWS_PER_WG + r;
    const int cb   = c * COLS_PER_LANE;

    const float dtf = tau[0] / 10.0f;

    // ---- compute waves: stage weights as f32 (cvt to f64 at use, exact) ----
    float wxf[COLS_PER_LANE], wyf[COLS_PER_LANE];
    float brow = 0.0f, xrow = 0.0f;
    if (comp) {
        const float* px = Wx + row * DD + cb;
        const float* py = Wy + row * DD + cb;
        #pragma unroll
        for (int i = 0; i < COLS_PER_LANE / 4; ++i) {
            float4 a = *(const float4*)(px + 4 * i);
            wxf[4*i+0] = a.x; wxf[4*i+1] = a.y; wxf[4*i+2] = a.z; wxf[4*i+3] = a.w;
            float4 d2 = *(const float4*)(py + 4 * i);
            wyf[4*i+0] = d2.x; wyf[4*i+1] = d2.y; wyf[4*i+2] = d2.z; wyf[4*i+3] = d2.w;
        }
        #pragma unroll
        for (int i = 0; i < COLS_PER_LANE; ++i) {
            asm volatile("" : "+v"(wxf[i]));
            asm volatile("" : "+v"(wyf[i]));
        }
        brow = b[row];
        xrow = x0[row];                  // lane c==0 carries x_j[row]
        if (c == 0) out[row * (NSTEPS + 1) + 0] = xrow;
    }

    for (int j = 0; j < NSTEPS; ++j) {
        double doty = 0.0;
        if (comp) {
            // ---- delayed half: y = x_{j-10} from LDS history (frozen) ----
            double dy0 = 0.0, dy1 = 0.0;
            if (j <= 10) {
                const float* ys = x0 + cb;
                #pragma unroll
                for (int i = 0; i < COLS_PER_LANE / 4; ++i) {
                    float4 v = *(const float4*)(ys + 4 * i);
                    dy0 = fma((double)wyf[4*i+0], (double)v.x, dy0);
                    dy1 = fma((double)wyf[4*i+1], (double)v.y, dy1);
                    dy0 = fma((double)wyf[4*i+2], (double)v.z, dy0);
                    dy1 = fma((double)wyf[4*i+3], (double)v.w, dy1);
                }
            } else {
                const float* hs = hist[(j - 10) & (RING - 1)];
                #pragma unroll
                for (int k = 0; k < COLS_PER_LANE; k += 4) {
                    float v0 = hs[(k+0)*32 + c];
                    float v1 = hs[(k+1)*32 + c];
                    float v2 = hs[(k+2)*32 + c];
                    float v3 = hs[(k+3)*32 + c];
                    dy0 = fma((double)wyf[k+0], (double)v0, dy0);
                    dy1 = fma((double)wyf[k+1], (double)v1, dy1);
                    dy0 = fma((double)wyf[k+2], (double)v2, dy0);
                    dy1 = fma((double)wyf[k+3], (double)v3, dy1);
                }
            }
            doty = dy0 + dy1;
            #pragma unroll
            for (int off = 1; off < 32; off <<= 1)
                doty += __shfl_xor(doty, off);
        }

        // ---- ALL 6 waves: 1-load sweep of 2 adjacent packs each (exact
        // cover of 768), then broadcast to LDS. Fallback to 8B atomic polls
        // after 2048 tries (no-hang; semantics-independent). ----
        if (j >= 1) {
            const unsigned tgt = (unsigned)j;
            const unsigned long long* xs =
                ring + (j & (RING - 1)) * DD + 2 * tid;
            unsigned v0, v1;
            int tries = 0;
            for (;;) {
                bool ok;
                if (tries < 2048) {
                    u32x4 q = ld_pair(xs);
                    v0 = q.x; v1 = q.z;
                    ok = (q.y == tgt) & (q.w == tgt);
                } else {
                    unsigned long long q0 = ld_tag(xs + 0);
                    unsigned long long q1 = ld_tag(xs + 1);
                    v0 = (unsigned)q0; v1 = (unsigned)q1;
                    ok = ((unsigned)(q0 >> 32) == tgt) &
                         ((unsigned)(q1 >> 32) == tgt);
                }
                if (__all(ok)) break;
                ++tries;
            }
            float* hsw = hist[j & (RING - 1)];
            const int i0 = 2 * tid;
            hsw[((i0+0) % 24) * 32 + ((i0+0) / 24)] = __uint_as_float(v0);
            hsw[((i0+1) % 24) * 32 + ((i0+1) / 24)] = __uint_as_float(v1);
            __syncthreads();
        }

        if (comp) {
            // ---- live half: Wx · x_j from LDS (frozen) ----
            double dx0 = 0.0, dx1 = 0.0;
            if (j == 0) {
                const float* xs = x0 + cb;
                #pragma unroll
                for (int i = 0; i < COLS_PER_LANE / 4; ++i) {
                    float4 v = *(const float4*)(xs + 4 * i);
                    dx0 = fma((double)wxf[4*i+0], (double)v.x, dx0);
                    dx1 = fma((double)wxf[4*i+1], (double)v.y, dx1);
                    dx0 = fma((double)wxf[4*i+2], (double)v.z, dx0);
                    dx1 = fma((double)wxf[4*i+3], (double)v.w, dx1);
                }
            } else {
                const float* hs = hist[j & (RING - 1)];
                #pragma unroll
                for (int k = 0; k < COLS_PER_LANE; k += 4) {
                    float v0 = hs[(k+0)*32 + c];
                    float v1 = hs[(k+1)*32 + c];
                    float v2 = hs[(k+2)*32 + c];
                    float v3 = hs[(k+3)*32 + c];
                    dx0 = fma((double)wxf[k+0], (double)v0, dx0);
                    dx1 = fma((double)wxf[k+1], (double)v1, dx1);
                    dx0 = fma((double)wxf[k+2], (double)v2, dx0);
                    dx1 = fma((double)wxf[k+3], (double)v3, dx1);
                }
            }
            double dotx = dx0 + dx1;
            #pragma unroll
            for (int off = 1; off < 32; off <<= 1)
                dotx += __shfl_xor(dotx, off);

            if (c == 0) {
                // z = (dot1_f32 + dot2_f32) + b, all fp32 adds (frozen)
                float z = __fadd_rn(__fadd_rn((float)dotx, (float)doty), brow);
                float th;
                float az = fabsf(z);
                if (az < 9.3f) th = (float)tanh((double)z);  // correctly-rounded
                else           th = (z > 0.0f) ? 1.0f : -1.0f;
                // x_next = x + dt*F, fp32 mul then fp32 add (frozen)
                xrow = __fadd_rn(xrow, __fmul_rn(dtf, th));

                // publish: (value|tag) in one relaxed agent-scope 8B store
                unsigned long long pack =
                    ((unsigned long long)(unsigned)(j + 1) << 32) |
                    (unsigned long long)__float_as_uint(xrow);
                __hip_atomic_store(&ring[((j + 1) & (RING - 1)) * DD + row],
                                   pack, __ATOMIC_RELAXED,
                                   __HIP_MEMORY_SCOPE_AGENT);

                // trajectory write — off the critical path
                out[row * (NSTEPS + 1) + (j + 1)] = xrow;
            }
        }
    }
}

extern "C" void kernel_launch(void* const* d_in, const int* in_sizes, int n_in,
                              void* d_out, int out_size, void* d_ws, size_t ws_size,
                              hipStream_t stream) {
    (void)in_sizes; (void)n_in; (void)out_size; (void)ws_size;

    const float* x0  = (const float*)d_in[0];
    const float* tau = (const float*)d_in[1];
    const float* Wx  = (const float*)d_in[2];
    const float* Wy  = (const float*)d_in[3];
    const float* b   = (const float*)d_in[4];
    float* out = (float*)d_out;

    unsigned long long* ring = (unsigned long long*)((char*)d_ws + RING_OFF);

    // No memset needed: strict tag==j matching rejects 0xAA poison and stale
    // replay tags (slot j%16 is freshly rewritten long before step j needs it).
    ndde_kernel<<<NWG, NT, 0, stream>>>(x0, tau, Wx, Wy, b, out, ring);
}

// Round 13
// 14246.249 us; speedup vs baseline: 1.2550x; 1.2550x over previous
//
#include <hip/hip_runtime.h>
#include <math.h>

// NDDE forward-Euler DDE solve, D=768, N=8192 steps.
// x_{j+1} = x_j + dt * tanh(Wx x_j + Wy x_{j-10} + b),  dt = tau/10.
// Output: trajectory [D][N+1] fp32, out[i*(N+1)+k] = x_k[i].
//
// NUMERICS ARE FROZEN (passes at absmax 16.0 / thr 16.4): fp64-exact dots
// rounded per-dot to fp32; fp32 adds for z; correctly-rounded fp32 tanh via
// fp64; fp32 state update mul-then-add; per-row 32-lane x 24-col ownership,
// FMA order and shuffle tree IDENTICAL to rounds 5/11 (14.95 ms best).
//
// Round 13 = r11 topology (96 WGs x 256 thr, 4 waves, ALL waves compute and
// poll only inside the waiting window — r12 proved background spinner waves
// poison the publish path) + two changes:
//  1. 1-RT sweep: each thread's 3 packs via dwordx4 {2t,2t+1} + dwordx2
//     {512+t}, both issued then ONE vmcnt(0) (r11's 3 atomic loads were
//     serialized sub-RTs; r12 validated sc0 sc1 load semantics). Fallback
//     to r11's atomic-load poll after 2048 tries (no-hang).
//  2. LDS stride 32->33: kills the 24-way broadcast-write bank conflicts
//     (1.3e8 counter); dot reads stay conflict-free (bank=(k+c)%32).
//
// Encoded lessons: no fences (r3), no RMWs (r7), no extra detect hop (r9),
// no setprio on spinners (r6), no replication (r8), no pure-poller waves
// (r6/r12), VGPR must fit weights (r4/r10).

#define DD 768
#define NSTEPS 8192
#define NWG 96
#define NT 256
#define ROWS_PER_WG 8
#define COLS_PER_LANE 24
#define RING 16
#define LSTRIDE 33
#define LSLOT (COLS_PER_LANE * LSTRIDE)   // 792 words per history slot

#define RING_OFF 0   // RING * DD * 8B packs in d_ws

typedef __attribute__((ext_vector_type(4))) unsigned int u32x4;
typedef __attribute__((ext_vector_type(2))) unsigned int u32x2;

__device__ __forceinline__ unsigned long long ld_tag(const unsigned long long* p) {
    return __hip_atomic_load(p, __ATOMIC_RELAXED, __HIP_MEMORY_SCOPE_AGENT);
}

// One sweep: both poll loads in flight, single wait. sc0 sc1 -> coherent
// read at the device coherence point (validated by r12's correct runs).
__device__ __forceinline__ void sweep_ld(const unsigned long long* p4,
                                         const unsigned long long* p2,
                                         u32x4* q, u32x2* r2) {
    asm volatile("global_load_dwordx4 %0, %2, off sc0 sc1\n\t"
                 "global_load_dwordx2 %1, %3, off sc0 sc1\n\t"
                 "s_waitcnt vmcnt(0)"
                 : "=&v"(*q), "=&v"(*r2)
                 : "v"(p4), "v"(p2)
                 : "memory");
}

__global__ __launch_bounds__(NT, 1)
void ndde_kernel(const float* __restrict__ x0,
                 const float* __restrict__ tau,
                 const float* __restrict__ Wx,
                 const float* __restrict__ Wy,
                 const float* __restrict__ b,
                 float* __restrict__ out,
                 unsigned long long* __restrict__ ring)
{
    // Padded transposed f32 LDS history: column i at
    // hist[slot*LSLOT + (i%24)*33 + i/24]. Dot-read bank = (k+c)%32:
    // conflict-free across the 32 lanes of a half-wave (2-way across the
    // full wave = free). Broadcast writes scatter ~6-way (vs 24-way at
    // stride 32 — the 1.3e8 SQ_LDS_BANK_CONFLICT in r11/r12).
    __shared__ float hist[RING * LSLOT];          // 50.7 KB

    const int tid = threadIdx.x;
    const int g   = blockIdx.x;
    const int r   = tid >> 5;            // local row 0..7
    const int c   = tid & 31;            // lane-within-row 0..31
    const int row = g * ROWS_PER_WG + r;
    const int cb  = c * COLS_PER_LANE;

    const float dtf = tau[0] / 10.0f;

    // ---- stage weights as f32 (cvt to f64 at use, exact) ----
    float wxf[COLS_PER_LANE], wyf[COLS_PER_LANE];
    {
        const float* px = Wx + row * DD + cb;
        const float* py = Wy + row * DD + cb;
        #pragma unroll
        for (int i = 0; i < COLS_PER_LANE / 4; ++i) {
            float4 a = *(const float4*)(px + 4 * i);
            wxf[4*i+0] = a.x; wxf[4*i+1] = a.y; wxf[4*i+2] = a.z; wxf[4*i+3] = a.w;
            float4 d2 = *(const float4*)(py + 4 * i);
            wyf[4*i+0] = d2.x; wyf[4*i+1] = d2.y; wyf[4*i+2] = d2.z; wyf[4*i+3] = d2.w;
        }
    }
    #pragma unroll
    for (int i = 0; i < COLS_PER_LANE; ++i) {
        asm volatile("" : "+v"(wxf[i]));
        asm volatile("" : "+v"(wyf[i]));
    }

    const float brow = b[row];
    float xrow = x0[row];                // lane c==0 carries x_j[row]
    if (c == 0) out[row * (NSTEPS + 1) + 0] = xrow;

    for (int j = 0; j < NSTEPS; ++j) {
        // ---- delayed half: y = x_{j-10} from LDS history (frozen math) ----
        double dy0 = 0.0, dy1 = 0.0;
        if (j <= 10) {
            const float* ys = x0 + cb;
            #pragma unroll
            for (int i = 0; i < COLS_PER_LANE / 4; ++i) {
                float4 v = *(const float4*)(ys + 4 * i);
                dy0 = fma((double)wyf[4*i+0], (double)v.x, dy0);
                dy1 = fma((double)wyf[4*i+1], (double)v.y, dy1);
                dy0 = fma((double)wyf[4*i+2], (double)v.z, dy0);
                dy1 = fma((double)wyf[4*i+3], (double)v.w, dy1);
            }
        } else {
            const float* hs = hist + ((j - 10) & (RING - 1)) * LSLOT;
            #pragma unroll
            for (int k = 0; k < COLS_PER_LANE; k += 4) {
                float v0 = hs[(k+0)*LSTRIDE + c];
                float v1 = hs[(k+1)*LSTRIDE + c];
                float v2 = hs[(k+2)*LSTRIDE + c];
                float v3 = hs[(k+3)*LSTRIDE + c];
                dy0 = fma((double)wyf[k+0], (double)v0, dy0);
                dy1 = fma((double)wyf[k+1], (double)v1, dy1);
                dy0 = fma((double)wyf[k+2], (double)v2, dy0);
                dy1 = fma((double)wyf[k+3], (double)v3, dy1);
            }
        }
        double doty = dy0 + dy1;
        #pragma unroll
        for (int off = 1; off < 32; off <<= 1)
            doty += __shfl_xor(doty, off);

        // ---- ALL 4 waves: 1-RT sweep of 3 packs/thread (2 requests, one
        // wait), disjoint cover of 768, broadcast to LDS, barrier ----
        if (j >= 1) {
            const unsigned tgt = (unsigned)j;
            const unsigned long long* base = ring + (j & (RING - 1)) * DD;
            const unsigned long long* p4 = base + 2 * tid;      // packs 2t,2t+1
            const unsigned long long* p2 = base + 512 + tid;    // pack 512+t
            unsigned v0, v1, v2;
            int tries = 0;
            for (;;) {
                bool ok;
                if (tries < 2048) {
                    u32x4 q; u32x2 s;
                    sweep_ld(p4, p2, &q, &s);
                    v0 = q.x; v1 = q.z; v2 = s.x;
                    ok = (q.y == tgt) & (q.w == tgt) & (s.y == tgt);
                } else {               // r11-proven fallback (no-hang)
                    unsigned long long q0 = ld_tag(p4 + 0);
                    unsigned long long q1 = ld_tag(p4 + 1);
                    unsigned long long q2 = ld_tag(p2);
                    v0 = (unsigned)q0; v1 = (unsigned)q1; v2 = (unsigned)q2;
                    ok = ((unsigned)(q0 >> 32) == tgt) &
                         ((unsigned)(q1 >> 32) == tgt) &
                         ((unsigned)(q2 >> 32) == tgt);
                }
                if (__all(ok)) break;
                ++tries;
            }
            float* hsw = hist + (j & (RING - 1)) * LSLOT;
            const int iA = 2 * tid, iB = 2 * tid + 1, iC = 512 + tid;
            hsw[(iA % 24) * LSTRIDE + (iA / 24)] = __uint_as_float(v0);
            hsw[(iB % 24) * LSTRIDE + (iB / 24)] = __uint_as_float(v1);
            hsw[(iC % 24) * LSTRIDE + (iC / 24)] = __uint_as_float(v2);
            __syncthreads();
        }

        // ---- live half: Wx · x_j from LDS (frozen math) ----
        double dx0 = 0.0, dx1 = 0.0;
        if (j == 0) {
            const float* xs = x0 + cb;
            #pragma unroll
            for (int i = 0; i < COLS_PER_LANE / 4; ++i) {
                float4 v = *(const float4*)(xs + 4 * i);
                dx0 = fma((double)wxf[4*i+0], (double)v.x, dx0);
                dx1 = fma((double)wxf[4*i+1], (double)v.y, dx1);
                dx0 = fma((double)wxf[4*i+2], (double)v.z, dx0);
                dx1 = fma((double)wxf[4*i+3], (double)v.w, dx1);
            }
        } else {
            const float* hs = hist + (j & (RING - 1)) * LSLOT;
            #pragma unroll
            for (int k = 0; k < COLS_PER_LANE; k += 4) {
                float v0 = hs[(k+0)*LSTRIDE + c];
                float v1 = hs[(k+1)*LSTRIDE + c];
                float v2 = hs[(k+2)*LSTRIDE + c];
                float v3 = hs[(k+3)*LSTRIDE + c];
                dx0 = fma((double)wxf[k+0], (double)v0, dx0);
                dx1 = fma((double)wxf[k+1], (double)v1, dx1);
                dx0 = fma((double)wxf[k+2], (double)v2, dx0);
                dx1 = fma((double)wxf[k+3], (double)v3, dx1);
            }
        }
        double dotx = dx0 + dx1;
        #pragma unroll
        for (int off = 1; off < 32; off <<= 1)
            dotx += __shfl_xor(dotx, off);

        if (c == 0) {
            // z = (dot1_f32 + dot2_f32) + b, all fp32 adds (frozen)
            float z = __fadd_rn(__fadd_rn((float)dotx, (float)doty), brow);
            float th;
            float az = fabsf(z);
            if (az < 9.3f) th = (float)tanh((double)z);  // correctly-rounded
            else           th = (z > 0.0f) ? 1.0f : -1.0f;
            // x_next = x + dt*F, fp32 mul then fp32 add (frozen)
            xrow = __fadd_rn(xrow, __fmul_rn(dtf, th));

            // publish: (value|tag) in one relaxed agent-scope 8B store
            unsigned long long pack =
                ((unsigned long long)(unsigned)(j + 1) << 32) |
                (unsigned long long)__float_as_uint(xrow);
            __hip_atomic_store(&ring[((j + 1) & (RING - 1)) * DD + row], pack,
                               __ATOMIC_RELAXED, __HIP_MEMORY_SCOPE_AGENT);

            // trajectory write — off the critical path
            out[row * (NSTEPS + 1) + (j + 1)] = xrow;
        }
    }
}

extern "C" void kernel_launch(void* const* d_in, const int* in_sizes, int n_in,
                              void* d_out, int out_size, void* d_ws, size_t ws_size,
                              hipStream_t stream) {
    (void)in_sizes; (void)n_in; (void)out_size; (void)ws_size;

    const float* x0  = (const float*)d_in[0];
    const float* tau = (const float*)d_in[1];
    const float* Wx  = (const float*)d_in[2];
    const float* Wy  = (const float*)d_in[3];
    const float* b   = (const float*)d_in[4];
    float* out = (float*)d_out;

    unsigned long long* ring = (unsigned long long*)((char*)d_ws + RING_OFF);

    // No memset needed: strict tag==j matching rejects 0xAA poison and stale
    // replay tags (slot j%16 is freshly rewritten long before step j needs it).
    ndde_kernel<<<NWG, NT, 0, stream>>>(x0, tau, Wx, Wy, b, out, ring);
}